// Round 8
// baseline (240.408 us; speedup 1.0000x reference)
//
#include <hip/hip_runtime.h>
#include <math.h>

#define KK 256
#define NN 65536
#define TT 128   // time-tile columns per block; 67.6KB LDS -> 2 blocks/CU
#define TPAD 264 // 256 + 8 bf16 pad: breaks 512B-stride bank aliasing, keeps 16B align
#define NB (NN / TT)  // 512 blocks

typedef __bf16 bf16x8 __attribute__((ext_vector_type(8)));
typedef float f32x4 __attribute__((ext_vector_type(4)));

// ---------------------------------------------------------------------------
// Kernel 1: streamed rowsum -> mu0, Alpha -> bf16, zero loglik accumulator.
//   Block j: obs row j (256KB) as 512 thr x 32 float4 — pure sequential read.
// ---------------------------------------------------------------------------
__global__ __launch_bounds__(512) void prep_kernel(const float* __restrict__ obs,
                                                   const float* __restrict__ Alpha,
                                                   float* __restrict__ mu0,
                                                   __bf16* __restrict__ AlphaB,
                                                   float* __restrict__ out) {
  const int j = blockIdx.x;
  const int tid = threadIdx.x;
  if (tid < KK) AlphaB[(size_t)j * KK + tid] = (__bf16)Alpha[(size_t)j * KK + tid];
  const float4* p = (const float4*)(obs + (size_t)j * NN) + tid;
  float s = 0.f;
#pragma unroll
  for (int i = 0; i < 32; ++i) {
    float4 v = p[i * 512];
    s += (v.x + v.y) + (v.z + v.w);
  }
  __shared__ float red[512];
  red[tid] = s;
  __syncthreads();
  for (int off = 256; off > 0; off >>= 1) {
    if (tid < off) red[tid] += red[tid + off];
    __syncthreads();
  }
  if (tid == 0) {
    mu0[j] = red[0] * (1.0f / NN) * 0.1f + 0.01f;
    if (j == 0) out[0] = 0.f;  // loglik accumulator (d_out poisoned between runs)
  }
}

// ---------------------------------------------------------------------------
// Kernel 2: fused wave-coop scan + bf16-MFMA GEMM + softplus + lams1 store +
//           loglik (mu0 from LDS, obs re-read L2-hot: ~7MB extra HBM, R3).
//   Scan: octet-per-row; 8 lanes share row k, lane l owns t = 8*rnd + l.
//   Per 8-col round: Hillis-Steele weighted scan (3 masked shfl_up), then
//   H[base+l] = d^l*Hc + d*I_{l-1}; carry Hc' = d^8*Hc + d*I_7. Identical
//   algebra to serial scan (validated R6). 16-col window: tail err < e^-16.
//   XCD swizzle: each XCD covers a contiguous 8192-col span.
// ---------------------------------------------------------------------------
__global__ __launch_bounds__(512, 4) void main_kernel(const float* __restrict__ obs,
                                                      const float* __restrict__ Beta,
                                                      const float* __restrict__ mu0,
                                                      const __bf16* __restrict__ AlphaB,
                                                      float* __restrict__ out) {
  __shared__ __bf16 Slds[TT][TPAD];  // 67.6 KB
  __shared__ float mu0s[KK];         // +1 KB
  const int tid = threadIdx.x;
  const int bid = blockIdx.x;
  const int tb = ((bid & 7) << 6) | (bid >> 3);  // bijective XCD swizzle (512 blocks)
  const int t0 = tb * TT;

  if (tid < KK) mu0s[tid] = mu0[tid];

  // ---- scan phase: 64 rows in flight (8 lanes each), 4 row-iterations ----
  {
    const int ell = tid & 7;
    const int krow0 = tid >> 3;  // 0..63
    for (int it = 0; it < 4; ++it) {
      const int k = it * 64 + krow0;
      const float beta = Beta[k];
      const float d = expf(-beta);
      const float d2 = d * d, d4 = d2 * d2, d8 = d4 * d4;
      float dl = 1.f;  // d^ell
      if (ell & 1) dl *= d;
      if (ell & 2) dl *= d2;
      if (ell & 4) dl *= d4;
      const float* row = obs + (size_t)k * NN;
      float Hc = 0.f;  // carry ~ H[t0]; 16-col window -> tail rel err < e^-16
      if (t0 > 0) {
#pragma unroll
        for (int rnd = 0; rnd < 2; ++rnd) {
          const float u = row[t0 - 16 + rnd * 8 + ell];
          float X = u, y;
          y = __shfl_up(X, 1, 8); X += (ell >= 1 ? d  * y : 0.f);
          y = __shfl_up(X, 2, 8); X += (ell >= 2 ? d2 * y : 0.f);
          y = __shfl_up(X, 4, 8); X += (ell >= 4 ? d4 * y : 0.f);
          const float I7 = __shfl(X, 7, 8);
          Hc = d8 * Hc + d * I7;
        }
      }
#pragma unroll
      for (int rnd = 0; rnd < 16; ++rnd) {
        const int base = 8 * rnd;  // relative to t0
        const float u = row[t0 + base + ell];
        float X = u, y;
        y = __shfl_up(X, 1, 8); X += (ell >= 1 ? d  * y : 0.f);
        y = __shfl_up(X, 2, 8); X += (ell >= 2 ? d2 * y : 0.f);
        y = __shfl_up(X, 4, 8); X += (ell >= 4 ? d4 * y : 0.f);
        const float Ip = __shfl_up(X, 1, 8);           // I_{ell-1}
        const float H = dl * Hc + (ell >= 1 ? d * Ip : 0.f);
        Slds[base + ell][k] = (__bf16)(beta * H);
        const float I7 = __shfl(X, 7, 8);
        Hc = d8 * Hc + d * I7;                         // H used old Hc above
      }
    }
  }
  __syncthreads();

  // ---- MFMA GEMM: wave (wj=w&3, wc=w>>2): j in [64wj,+64) x t in [64wc,+64) ----
  const int wave = tid >> 6;
  const int wj = wave & 3, wc = wave >> 2;
  const int lane = tid & 63;
  const int lquad = lane >> 4;  // k-octet within K=32 step / j-sub in C
  const int l16 = lane & 15;

  f32x4 acc[4][4];  // [jsub][tsub]
#pragma unroll
  for (int a = 0; a < 4; ++a)
#pragma unroll
    for (int b = 0; b < 4; ++b) acc[a][b] = (f32x4){0.f, 0.f, 0.f, 0.f};

  const __bf16* Abase = AlphaB + (size_t)(wj * 64 + l16) * KK + lquad * 8;
  for (int k0 = 0; k0 < KK; k0 += 32) {
    bf16x8 afrag[4], bfrag[4];
#pragma unroll
    for (int js = 0; js < 4; ++js)
      afrag[js] = *(const bf16x8*)(Abase + (size_t)js * 16 * KK + k0);
#pragma unroll
    for (int ts = 0; ts < 4; ++ts)
      bfrag[ts] = *(const bf16x8*)&Slds[wc * 64 + ts * 16 + l16][k0 + lquad * 8];
#pragma unroll
    for (int js = 0; js < 4; ++js)
#pragma unroll
      for (int ts = 0; ts < 4; ++ts)
        acc[js][ts] = __builtin_amdgcn_mfma_f32_16x16x32_bf16(
            afrag[js], bfrag[ts], acc[js][ts], 0, 0, 0);
  }

  // ---- epilogue: softplus + lams1 store + loglik (obs re-read L2-hot) ----
  float partial = 0.f;
  float* lams1 = out + 1 + (size_t)KK * NN;
  const int tcol = t0 + wc * 64;
#pragma unroll
  for (int js = 0; js < 4; ++js) {
#pragma unroll
    for (int r = 0; r < 4; ++r) {
      const int j = wj * 64 + js * 16 + lquad * 4 + r;  // D row mapping
      const float m = mu0s[j];
      const size_t rowoff = (size_t)j * NN + tcol + l16;
#pragma unroll
      for (int ts = 0; ts < 4; ++ts) {
        float v = acc[js][ts][r];                    // v >= 0 always
        float lam = v + __logf(1.f + __expf(-v));    // stable softplus
        if (tcol + ts * 16 + l16 == 0) lam = 0.f;    // lams1[:,0] = 0
        lams1[rowoff + ts * 16] = lam;
        const float o = obs[rowoff + ts * 16];       // L2-hot (scan just read it)
        partial += o * __logf(m + lam + 1e-5f) - m - lam;
      }
    }
  }

  // wave reduce -> block reduce -> one atomic per block (512 total)
#pragma unroll
  for (int off = 32; off > 0; off >>= 1)
    partial += __shfl_down(partial, off, 64);
  __syncthreads();  // all waves done reading Slds
  float* red = (float*)&Slds[0][0];
  if (lane == 0) red[wave] = partial;
  __syncthreads();
  if (tid == 0) {
    float t = 0.f;
#pragma unroll
    for (int w = 0; w < 8; ++w) t += red[w];
    atomicAdd(out, t);
  }
}

// ---------------------------------------------------------------------------
// Kernel 3: streamed lams0 fill: row j = mu0[j]. Pure sequential writes.
// ---------------------------------------------------------------------------
__global__ __launch_bounds__(512) void lams0_kernel(const float* __restrict__ mu0,
                                                    float* __restrict__ out) {
  const int j = blockIdx.x;
  const int tid = threadIdx.x;
  const float m = mu0[j];
  float* row0 = out + 1 + (size_t)j * NN;  // base 4B-misaligned: peel edges
  if (tid < 3) row0[tid] = m;
  if (tid == 3) row0[NN - 1] = m;
  f32x4* p4 = (f32x4*)(row0 + 3);  // 16B-aligned
  const f32x4 mv = {m, m, m, m};
  for (int i = tid; i < (NN - 4) / 4; i += 512) p4[i] = mv;
}

// ---------------------------------------------------------------------------
extern "C" void kernel_launch(void* const* d_in, const int* in_sizes, int n_in,
                              void* d_out, int out_size, void* d_ws, size_t ws_size,
                              hipStream_t stream) {
  const float* obs   = (const float*)d_in[0];
  const float* Beta  = (const float*)d_in[1];
  const float* Alpha = (const float*)d_in[2];
  float* out = (float*)d_out;

  __bf16* AlphaB = (__bf16*)d_ws;                     // 128 KB
  float* mu0 = (float*)(AlphaB + (size_t)KK * KK);    // 256 floats

  hipLaunchKernelGGL(prep_kernel, dim3(KK), dim3(512), 0, stream, obs, Alpha,
                     mu0, AlphaB, out);
  hipLaunchKernelGGL(main_kernel, dim3(NB), dim3(512), 0, stream,
                     obs, Beta, mu0, AlphaB, out);
  hipLaunchKernelGGL(lams0_kernel, dim3(KK), dim3(512), 0, stream, mu0, out);
}

// Round 9
// 235.273 us; speedup vs baseline: 1.0218x; 1.0218x over previous
//
#include <hip/hip_runtime.h>
#include <math.h>

#define KK 256
#define NN 65536
#define TT 256   // time-tile columns per block (1KB write run per row)
#define TPAD 264 // 256 + 8 bf16 pad: breaks 512B-stride bank aliasing, keeps 16B align
#define CP 260   // f32 C-bounce row pitch: mult of 4 (b128 align), 4*CP%32=16 -> 2-way
#define NB (NN / TT)  // 256 blocks, 1024 thr: 1 block/CU, 16 waves/CU (same as R6)

typedef __bf16 bf16x8 __attribute__((ext_vector_type(8)));
typedef float f32x4 __attribute__((ext_vector_type(4)));

// ---------------------------------------------------------------------------
// Kernel 1: Alpha -> bf16 convert, zero loglik accumulator (d_out poisoned).
// ---------------------------------------------------------------------------
__global__ __launch_bounds__(256) void alpha_kernel(const float* __restrict__ Alpha,
                                                    __bf16* __restrict__ AlphaB,
                                                    float* __restrict__ out) {
  const int i = blockIdx.x * 256 + threadIdx.x;
  AlphaB[i] = (__bf16)Alpha[i];
  if (i == 0) out[0] = 0.f;
}

// ---------------------------------------------------------------------------
// Kernel 2: fused wave-coop scan + rowsum + bf16-MFMA GEMM + softplus +
//           LDS-bounced streaming lams1 store.
//   1024 thr = 16 waves, TT=256, LDS 135KB -> 1 block/CU (16 waves/CU, same
//   occupancy as R6's 2x8). GEMM keeps LDS-cheap 4x4 wave tiling; the C-tile
//   is then bounced through LDS (2 halves of 128j x 256t f32 reusing Slds)
//   so each wave streams 8 COMPLETE 1KB rows: ds_read_b128 + 1KB
//   global_store_dwordx4 per row, wave-sequential 8KB runs per row-group.
//   XCD swizzle: 32 blocks/XCD cover a contiguous 8192-col span.
// ---------------------------------------------------------------------------
__global__ __launch_bounds__(1024, 4) void main_kernel(const float* __restrict__ obs,
                                                       const float* __restrict__ Beta,
                                                       const __bf16* __restrict__ AlphaB,
                                                       float* __restrict__ out,
                                                       float* __restrict__ P) {
  __shared__ __align__(16) __bf16 Slds[TT][TPAD];  // 135.2 KB; reused as C-bounce
  const int tid = threadIdx.x;
  const int bid = blockIdx.x;
  const int tb = ((bid & 7) << 5) | (bid >> 3);  // bijective: 256 blocks, 32/XCD
  const int t0 = tb * TT;

  // ---- scan: octet-per-row (validated R6). 128 rows in flight, 2 iters ----
  {
    const int ell = tid & 7;
    const int krow0 = tid >> 3;  // 0..127
    for (int it = 0; it < 2; ++it) {
      const int k = it * 128 + krow0;
      const float beta = Beta[k];
      const float d = expf(-beta);
      const float d2 = d * d, d4 = d2 * d2, d8 = d4 * d4;
      float dl = 1.f;  // d^ell
      if (ell & 1) dl *= d;
      if (ell & 2) dl *= d2;
      if (ell & 4) dl *= d4;
      const float* row = obs + (size_t)k * NN;
      float Hc = 0.f;  // carry ~ H[t0]; 16-col window -> tail rel err < e^-16
      if (t0 > 0) {
#pragma unroll
        for (int rnd = 0; rnd < 2; ++rnd) {
          const float u = row[t0 - 16 + rnd * 8 + ell];
          float X = u, y;
          y = __shfl_up(X, 1, 8); X += (ell >= 1 ? d  * y : 0.f);
          y = __shfl_up(X, 2, 8); X += (ell >= 2 ? d2 * y : 0.f);
          y = __shfl_up(X, 4, 8); X += (ell >= 4 ? d4 * y : 0.f);
          const float I7 = __shfl(X, 7, 8);
          Hc = d8 * Hc + d * I7;
        }
      }
      float rsum = 0.f;
#pragma unroll
      for (int rnd = 0; rnd < 32; ++rnd) {
        const int base = 8 * rnd;  // relative to t0
        const float u = row[t0 + base + ell];
        rsum += u;
        float X = u, y;
        y = __shfl_up(X, 1, 8); X += (ell >= 1 ? d  * y : 0.f);
        y = __shfl_up(X, 2, 8); X += (ell >= 2 ? d2 * y : 0.f);
        y = __shfl_up(X, 4, 8); X += (ell >= 4 ? d4 * y : 0.f);
        const float Ip = __shfl_up(X, 1, 8);           // I_{ell-1}
        const float H = dl * Hc + (ell >= 1 ? d * Ip : 0.f);
        Slds[base + ell][k] = (__bf16)(beta * H);
        const float I7 = __shfl(X, 7, 8);
        Hc = d8 * Hc + d * I7;                         // H used old Hc above
      }
      // octet rowsum reduce -> P[k][tb] (coalesced row-read in loglik)
      rsum += __shfl_down(rsum, 1, 8);
      rsum += __shfl_down(rsum, 2, 8);
      rsum += __shfl_down(rsum, 4, 8);
      if (ell == 0) P[(size_t)k * NB + tb] = rsum;
    }
  }
  __syncthreads();

  // ---- MFMA GEMM: wave (wj=w&3, wc=w>>2): j in [64wj,+64) x t in [64wc,+64) ----
  const int wave = tid >> 6;
  const int wj = wave & 3, wc = wave >> 2;
  const int lane = tid & 63;
  const int lquad = lane >> 4;  // k-octet within K=32 step / j-sub in C
  const int l16 = lane & 15;

  f32x4 acc[4][4];  // [jsub][tsub] (AGPRs)
#pragma unroll
  for (int a = 0; a < 4; ++a)
#pragma unroll
    for (int b = 0; b < 4; ++b) acc[a][b] = (f32x4){0.f, 0.f, 0.f, 0.f};

  const __bf16* Abase = AlphaB + (size_t)(wj * 64 + l16) * KK + lquad * 8;
  for (int k0 = 0; k0 < KK; k0 += 32) {
    bf16x8 afrag[4], bfrag[4];
#pragma unroll
    for (int js = 0; js < 4; ++js)
      afrag[js] = *(const bf16x8*)(Abase + (size_t)js * 16 * KK + k0);
#pragma unroll
    for (int ts = 0; ts < 4; ++ts)
      bfrag[ts] = *(const bf16x8*)&Slds[wc * 64 + ts * 16 + l16][k0 + lquad * 8];
#pragma unroll
    for (int js = 0; js < 4; ++js)
#pragma unroll
      for (int ts = 0; ts < 4; ++ts)
        acc[js][ts] = __builtin_amdgcn_mfma_f32_16x16x32_bf16(
            afrag[js], bfrag[ts], acc[js][ts], 0, 0, 0);
  }

  // ---- epilogue: softplus at dump; bounce C through LDS; stream 1KB rows ----
  float* Cl = (float*)&Slds[0][0];  // reuse as f32 [128][CP] (133.1 KB)
  float* lams1 = out + 1 + (size_t)KK * NN;
#pragma unroll
  for (int h = 0; h < 2; ++h) {
    __syncthreads();  // prior phase (GEMM reads / previous stream) done
    if ((wj >> 1) == h) {  // waves owning j-half h dump softplus'd lam
      const int jb = (wj & 1) * 64;
#pragma unroll
      for (int js = 0; js < 4; ++js) {
#pragma unroll
        for (int r = 0; r < 4; ++r) {
          const int jr = jb + js * 16 + lquad * 4 + r;  // row within half
#pragma unroll
          for (int ts = 0; ts < 4; ++ts) {
            const int tr = wc * 64 + ts * 16 + l16;     // col within tile
            float v = acc[js][ts][r];                   // v >= 0 always
            float lam = v + __logf(1.f + __expf(-v));   // stable softplus
            if (t0 + tr == 0) lam = 0.f;                // lams1[:,0] = 0
            Cl[jr * CP + tr] = lam;                     // 2-way banks (CP=260)
          }
        }
      }
    }
    __syncthreads();
    // stream: wave w writes rows h*128 + 8w .. +7, one 1KB store per row
#pragma unroll
    for (int rr = 0; rr < 8; ++rr) {
      const int jr = wave * 8 + rr;
      const f32x4 v = *(const f32x4*)&Cl[jr * CP + 4 * lane];
      *(f32x4*)&lams1[(size_t)(h * 128 + jr) * NN + t0 + 4 * lane] = v;
    }
  }
}

// ---------------------------------------------------------------------------
// Kernel 3: block j: reduce P[j][*] -> mu0_j; stream obs row j + lams1 row j,
//           write lams0 row j, loglik partial. One atomic per block.
//           Pure coalesced streams — measured 5.8 TB/s (R6).
// ---------------------------------------------------------------------------
__global__ __launch_bounds__(512) void loglik_kernel(const float* __restrict__ obs,
                                                     const float* __restrict__ P,
                                                     float* __restrict__ out) {
  const int j = blockIdx.x;
  const int tid = threadIdx.x;

  float s = (tid < NB) ? P[(size_t)j * NB + tid] : 0.f;  // coalesced 1KB row
  __shared__ float red[512];
  red[tid] = s;
  __syncthreads();
  for (int off = 256; off > 0; off >>= 1) {
    if (tid < off) red[tid] += red[tid + off];
    __syncthreads();
  }
  const float m = red[0] * (1.0f / NN) * 0.1f + 0.01f;

  const float* orow = obs + (size_t)j * NN;
  float* l0row = out + 1 + (size_t)j * NN;
  float* l1row = l0row + (size_t)KK * NN;
  float partial = 0.f;
#pragma unroll 8
  for (int i = 0; i < NN / 512; ++i) {
    const int t = tid + i * 512;          // coalesced scalar streams
    const float l1 = l1row[t];
    const float o = orow[t];
    l0row[t] = m;
    partial += o * __logf(m + l1 + 1e-5f) - m - l1;
  }

  // wave reduce -> block reduce -> one atomic (256 total)
#pragma unroll
  for (int off = 32; off > 0; off >>= 1)
    partial += __shfl_down(partial, off, 64);
  __syncthreads();
  if ((tid & 63) == 0) red[tid >> 6] = partial;
  __syncthreads();
  if (tid == 0) {
    float t = 0.f;
#pragma unroll
    for (int w = 0; w < 8; ++w) t += red[w];
    atomicAdd(out, t);
  }
}

// ---------------------------------------------------------------------------
extern "C" void kernel_launch(void* const* d_in, const int* in_sizes, int n_in,
                              void* d_out, int out_size, void* d_ws, size_t ws_size,
                              hipStream_t stream) {
  const float* obs   = (const float*)d_in[0];
  const float* Beta  = (const float*)d_in[1];
  const float* Alpha = (const float*)d_in[2];
  float* out = (float*)d_out;

  __bf16* AlphaB = (__bf16*)d_ws;                     // 128 KB
  float* P = (float*)(AlphaB + (size_t)KK * KK);      // 256 x 256 floats = 256 KB

  hipLaunchKernelGGL(alpha_kernel, dim3(KK), dim3(256), 0, stream, Alpha, AlphaB, out);
  hipLaunchKernelGGL(main_kernel, dim3(NB), dim3(1024), 0, stream,
                     obs, Beta, AlphaB, out, P);
  hipLaunchKernelGGL(loglik_kernel, dim3(KK), dim3(512), 0, stream, obs, P, out);
}